// Round 20
// baseline (63.298 us; speedup 1.0000x reference)
//
#include <hip/hip_runtime.h>
#include <math.h>

#define B_TOT   1024
#define L_SEQ   200
#define DIM     64
#define VOCAB   100001
#define NEG_BIG (-1e15f)
#define SEQ_ST16 66                     // bf16 row stride: 132 B -> 2-way (free) on both write & read
#define LOG2E   1.4426950408889634f
#define EB_SLACK_ROWS 512               // slack (kept; stage rows are clamped anyway)

typedef __bf16 bf16x8 __attribute__((ext_vector_type(8)));
typedef float  f32x4  __attribute__((ext_vector_type(4)));

// raw v_exp_f32 (exp2): inputs are bounded here, denormal guard unneeded
static __device__ __forceinline__ float fast_exp2(float x) {
    return __builtin_amdgcn_exp2f(x);
}

// ---------------------------------------------------------------------------
// Kernel A: attention pooling + tail-fused convert(E->bf16).  (R19 version:
// quarter-wave coalesced phase 1.)
// ---------------------------------------------------------------------------
__global__ __launch_bounds__(256) void pool_kernel(
    const int*   __restrict__ log_seqs,
    const float* __restrict__ item_emb,
    const float* __restrict__ attn_key,
    const float* __restrict__ pos_emb,
    float*       __restrict__ Q,
    __bf16*      __restrict__ Qb,
    __bf16*      __restrict__ Eb)
{
    const int b    = blockIdx.x;
    const int t    = threadIdx.x;
    const int wave = t >> 6;
    const int lane = t & 63;
    const int qw   = t >> 4;             // quarter-wave id 0..15
    const int ql   = t & 15;             // lane within quarter-wave

    __shared__ unsigned short s_seq16[L_SEQ][SEQ_ST16];  // 26,400 B
    __shared__ float s_sim[L_SEQ];
    __shared__ float s_attn[L_SEQ];
    __shared__ float s_red[4];
    __shared__ float s_q[4][DIM];

    // ---- phase 1: quarter-wave cooperative rows ---------------------------
    {
        const float4 key4 = ((const float4*)attn_key)[ql];   // coalesced
        const int* seq_row = log_seqs + (long)b * L_SEQ;
        #pragma unroll
        for (int it = 0; it < 13; ++it) {
            const int l = qw + it * 16;
            if (l >= L_SEQ) break;
            const int id = seq_row[l];                       // broadcast in qw
            float acc;
            if (id == 0) {
                *(ushort4*)&s_seq16[l][4 * ql] = make_ushort4(0, 0, 0, 0);
                acc = 0.f;
            } else {
                const float4 e = *(const float4*)(item_emb + (long)id * DIM + 4 * ql);
                const float4 p = *(const float4*)(pos_emb + l * DIM + 4 * ql);
                float4 f;
                f.x = fmaf(8.f, e.x, p.x);
                f.y = fmaf(8.f, e.y, p.y);
                f.z = fmaf(8.f, e.z, p.z);
                f.w = fmaf(8.f, e.w, p.w);
                ushort4 u;
                u.x = __builtin_bit_cast(unsigned short, (__bf16)f.x);
                u.y = __builtin_bit_cast(unsigned short, (__bf16)f.y);
                u.z = __builtin_bit_cast(unsigned short, (__bf16)f.z);
                u.w = __builtin_bit_cast(unsigned short, (__bf16)f.w);
                *(ushort4*)&s_seq16[l][4 * ql] = u;
                acc = f.x * key4.x + f.y * key4.y + f.z * key4.z + f.w * key4.w;
            }
            acc += __shfl_xor(acc, 1);
            acc += __shfl_xor(acc, 2);
            acc += __shfl_xor(acc, 4);
            acc += __shfl_xor(acc, 8);
            if (ql == 0) s_sim[l] = (id == 0) ? NEG_BIG : acc;
        }
    }
    __syncthreads();

    // ---- phase 2: block softmax over l -------------------------------------
    float sim = (t < L_SEQ) ? s_sim[t] : -INFINITY;
    float m = sim;
    #pragma unroll
    for (int off = 32; off > 0; off >>= 1) m = fmaxf(m, __shfl_xor(m, off));
    if (lane == 0) s_red[wave] = m;
    __syncthreads();
    m = fmaxf(fmaxf(s_red[0], s_red[1]), fmaxf(s_red[2], s_red[3]));
    __syncthreads();                             // all waves read s_red

    float p = (t < L_SEQ) ? __expf(sim - m) : 0.f;
    if (t < L_SEQ) s_attn[t] = p;
    float ls = p;
    #pragma unroll
    for (int off = 32; off > 0; off >>= 1) ls += __shfl_xor(ls, off);
    if (lane == 0) s_red[wave] = ls;
    __syncthreads();
    const float inv = 1.0f / (s_red[0] + s_red[1] + s_red[2] + s_red[3]);

    // ---- phase 3: Q accumulation from LDS, L split across waves ------------
    float q = 0.f;
    const int l0 = wave * (L_SEQ / 4);
    #pragma unroll 2
    for (int l = l0; l < l0 + (L_SEQ / 4); ++l) {
        const unsigned int ui = (unsigned int)s_seq16[l][lane] << 16;
        q = fmaf(s_attn[l], __builtin_bit_cast(float, ui), q);
    }
    s_q[wave][lane] = q;
    __syncthreads();

    if (t < DIM) {
        const float qq = (s_q[0][t] + s_q[1][t] + s_q[2][t] + s_q[3][t]) * inv;
        Q[b * DIM + t]  = qq;
        Qb[b * DIM + t] = (__bf16)(qq * LOG2E);  // exp2-domain for logits kernel
    }

    // ---- tail: convert slice of item_emb -> bf16 ---------------------------
    {
        const long n8 = ((long)VOCAB * DIM) / 8;             // 800,008 groups
        for (long g = (long)b * 256 + t; g < n8; g += (long)gridDim.x * 256) {
            const long i = g * 8;
            const float4 f0 = ((const float4*)(item_emb + i))[0];
            const float4 f1 = ((const float4*)(item_emb + i))[1];
            bf16x8 o;
            o[0] = (__bf16)f0.x; o[1] = (__bf16)f0.y; o[2] = (__bf16)f0.z; o[3] = (__bf16)f0.w;
            o[4] = (__bf16)f1.x; o[5] = (__bf16)f1.y; o[6] = (__bf16)f1.z; o[7] = (__bf16)f1.w;
            *(bf16x8*)(Eb + i) = o;
        }
    }
}

// ---------------------------------------------------------------------------
// Kernel B: bf16 MFMA logits GEMM + exp2-sum partials (R16 structure +
// T14 async-STAGE split).  Per phase:
//    barrier -> ds_write regs (loads landed during prev compute)
//            -> ISSUE next phase's global loads (row-clamped)
//    barrier -> compute (overlaps the in-flight loads)
// The global L2/L3 latency moves off the barrier-to-barrier critical path.
//  - block = 4 waves, 128 batch rows; wave w owns b-tiles {2w, 2w+1}
//  - XOR-swizzle slot ^= (row&7)<<4 on write & read
//  - NC=256 -> grid 2048 = 8 blocks/CU; tail vtile masks valid?:0
// XCD decode: chunk == xcd (mod 8); L2-resident chunk working set.
// ---------------------------------------------------------------------------
#define NC        256                   // vocab chunks
#define NBG       8                     // batch groups (1024/128)
#define VT_TOTAL  6251                  // ceil(100001/16)
#define VT_FULL   6250
#define VT_PER    25                    // ceil(VT_TOTAL/NC)
#define STAGE_VT  8                     // vtiles per stage phase (16 KB)

__global__ __launch_bounds__(256) void logits_mfma(
    const __bf16* __restrict__ Eb,      // [VOCAB+slack][64]
    const __bf16* __restrict__ Qb,      // [1024][64], exp2-domain
    float*        __restrict__ partials) // [NC][1024]
{
    const int bid   = blockIdx.x;                 // 0..2047
    const int xcd   = bid & 7;          // HW round-robins blockIdx across XCDs
    const int idx   = bid >> 3;         // 0..255 within this XCD
    const int chunk = xcd + 8 * (idx >> 3);       // chunks == xcd (mod 8)
    const int bg    = idx & 7;
    const int tid   = threadIdx.x;
    const int wave  = tid >> 6;
    const int lane  = tid & 63;
    const int r16   = lane & 15;
    const int hi    = lane >> 4;

    __shared__ char s_stage[STAGE_VT * 2048];     // 16,384 B

    bf16x8 a[2][2];
    #pragma unroll
    for (int t = 0; t < 2; ++t)
        #pragma unroll
        for (int s = 0; s < 2; ++s)
            a[t][s] = *(const bf16x8*)(Qb + ((bg*128 + (wave*2 + t)*16 + r16) * DIM) + s*32 + hi*8);

    const int vt0    = chunk * VT_PER;
    const int vt_end = min(vt0 + VT_PER, VT_TOTAL);
    const int nvt    = vt_end - vt0;
    const int nphase = nvt > 0 ? (nvt + STAGE_VT - 1) / STAGE_VT : 0;

    float ssum[2][4];
    #pragma unroll
    for (int t = 0; t < 2; ++t)
        #pragma unroll
        for (int r = 0; r < 4; ++r) ssum[t][r] = 0.f;

    // swizzled read offsets for this lane's fragment (within a 2 KB vtile)
    const int rbase = r16 * 128;
    const int x0 = (hi * 16)        ^ ((r16 & 7) << 4);
    const int x1 = ((hi * 16) + 64) ^ ((r16 & 7) << 4);

    // this thread's 4 stage items: row-group rowg, slot within row
    const int rowg = tid >> 1;                    // shared by k via +128 rows? no:
    // item k covers g = k*256 + tid -> rowg_k = g>>3, slot_k = g&7
    // (computed inline below; rows clamped so loads always in-bounds)

    // T14: issue loads for phase ph into regs
    bf16x8 v[4];
    #define ISSUE(ph_vtg0) do {                                               \
        _Pragma("unroll")                                                     \
        for (int k = 0; k < 4; ++k) {                                         \
            const int g     = k * 256 + tid;      /* 0..1023 */               \
            const int rg    = g >> 3;             /* 0..127 */                \
            const int slot  = g & 7;                                          \
            const int srow  = min((ph_vtg0) * 16 + rg, VOCAB - 1);            \
            v[k] = *(const bf16x8*)(Eb + (size_t)srow * DIM + slot * 8);      \
        }                                                                     \
    } while (0)

    if (nphase > 0) ISSUE(vt0);

    for (int ph = 0; ph < nphase; ++ph) {
        const int vtg0 = vt0 + ph * STAGE_VT;
        __syncthreads();                          // prev compute done before overwrite
        // write landed regs -> LDS (swizzled)
        #pragma unroll
        for (int k = 0; k < 4; ++k) {
            const int g    = k * 256 + tid;
            const int rg   = g >> 3;              // 0..127
            const int slot = g & 7;
            const int row  = rg & 15;
            const int vl   = rg >> 4;
            const int db   = vl * 2048 + row * 128 + ((slot * 16) ^ ((row & 7) << 4));
            *(bf16x8*)(s_stage + db) = v[k];
        }
        // issue NEXT phase's loads (latency hides under this phase's compute)
        ISSUE(vtg0 + STAGE_VT);
        __syncthreads();                          // staged data visible

        const int nv = min(STAGE_VT, vt_end - vtg0);
        for (int vl = 0; vl < nv; ++vl) {
            const char* vb = s_stage + vl * 2048 + rbase;
            const bf16x8 c0 = *(const bf16x8*)(vb + x0);
            const bf16x8 c1 = *(const bf16x8*)(vb + x1);
            const int vt_g = vtg0 + vl;
            if (vt_g < VT_FULL) {
                #pragma unroll
                for (int t = 0; t < 2; ++t) {
                    f32x4 acc = {0.f, 0.f, 0.f, 0.f};
                    acc = __builtin_amdgcn_mfma_f32_16x16x32_bf16(a[t][0], c0, acc, 0, 0, 0);
                    acc = __builtin_amdgcn_mfma_f32_16x16x32_bf16(a[t][1], c1, acc, 0, 0, 0);
                    #pragma unroll
                    for (int r = 0; r < 4; ++r) ssum[t][r] += fast_exp2(acc[r]);
                }
            } else {
                const bool valid = (vt_g * 16 + r16) < VOCAB;
                #pragma unroll
                for (int t = 0; t < 2; ++t) {
                    f32x4 acc = {0.f, 0.f, 0.f, 0.f};
                    acc = __builtin_amdgcn_mfma_f32_16x16x32_bf16(a[t][0], c0, acc, 0, 0, 0);
                    acc = __builtin_amdgcn_mfma_f32_16x16x32_bf16(a[t][1], c1, acc, 0, 0, 0);
                    #pragma unroll
                    for (int r = 0; r < 4; ++r) ssum[t][r] += valid ? fast_exp2(acc[r]) : 0.f;
                }
            }
        }
    }
    #undef ISSUE

    // reduce exp-sums across the 16 vocab cols (lanes differing in bits 0..3)
    #pragma unroll
    for (int t = 0; t < 2; ++t)
        #pragma unroll
        for (int r = 0; r < 4; ++r) {
            float s = ssum[t][r];
            s += __shfl_xor(s, 1);
            s += __shfl_xor(s, 2);
            s += __shfl_xor(s, 4);
            s += __shfl_xor(s, 8);
            ssum[t][r] = s;
        }

    // waves own disjoint rows -> direct write, no cross-wave reduce
    if (r16 == 0 && nphase > 0) {
        #pragma unroll
        for (int t = 0; t < 2; ++t)
            #pragma unroll
            for (int r = 0; r < 4; ++r) {
                const int row = bg * 128 + (wave*2 + t) * 16 + hi * 4 + r;
                partials[(size_t)chunk * B_TOT + row] = ssum[t][r];
            }
    }
    // chunks with nphase==0 (>= ceil(VT_TOTAL/VT_PER)) have all-zero ssum and
    // must still write zeros so finalize's fixed-order sum sees initialized
    // memory:
    if (r16 == 0 && nphase == 0) {
        #pragma unroll
        for (int t = 0; t < 2; ++t)
            #pragma unroll
            for (int r = 0; r < 4; ++r) {
                const int row = bg * 128 + (wave*2 + t) * 16 + hi * 4 + r;
                partials[(size_t)chunk * B_TOT + row] = 0.f;
            }
    }
}

// ---------------------------------------------------------------------------
// Kernel C: reduce partials, exact fp32 pred logit, emit prob.
// ---------------------------------------------------------------------------
__global__ __launch_bounds__(256) void finalize_kernel(
    const float* __restrict__ Q,
    const float* __restrict__ item_emb,
    const int*   __restrict__ pred,
    const float* __restrict__ partials,
    float*       __restrict__ out)
{
    const int b = blockIdx.x * 256 + threadIdx.x;

    float S = 0.f;
    for (int c = 0; c < NC; ++c)
        S += partials[(size_t)c * B_TOT + b];

    const int pv = pred[b];
    float acc = 0.f;
    const float4* e4 = (const float4*)(item_emb + (long)pv * DIM);
    const float4* q4 = (const float4*)(Q + b * DIM);
    #pragma unroll
    for (int i = 0; i < DIM / 4; ++i) {
        const float4 e = e4[i];
        const float4 q = q4[i];
        acc += e.x*q.x + e.y*q.y + e.z*q.z + e.w*q.w;
    }
    out[b] = __expf(acc) / S;
}

// ---------------------------------------------------------------------------
extern "C" void kernel_launch(void* const* d_in, const int* in_sizes, int n_in,
                              void* d_out, int out_size, void* d_ws, size_t ws_size,
                              hipStream_t stream)
{
    const int*   log_seqs = (const int*)  d_in[0];
    const int*   pred     = (const int*)  d_in[1];
    const float* item_emb = (const float*)d_in[2];
    const float* attn_key = (const float*)d_in[3];
    const float* pos_emb  = (const float*)d_in[4];
    float*       out      = (float*)d_out;

    char* ws = (char*)d_ws;
    const size_t eb_bytes = (size_t)(VOCAB + EB_SLACK_ROWS) * DIM * 2;  // + slack
    __bf16* Eb       = (__bf16*)ws;
    __bf16* Qb       = (__bf16*)(ws + eb_bytes);                        // 131,072 B
    float*  Qf       = (float*) (ws + eb_bytes + (size_t)B_TOT * DIM * 2);
    float*  partials = (float*) ((char*)Qf + (size_t)B_TOT * DIM * 4);  // [256][1024] f32

    pool_kernel<<<B_TOT, 256, 0, stream>>>(log_seqs, item_emb, attn_key, pos_emb, Qf, Qb, Eb);
    logits_mfma<<<NBG * NC, 256, 0, stream>>>(Eb, Qb, partials);
    finalize_kernel<<<B_TOT / 256, 256, 0, stream>>>(Qf, item_emb, pred, partials, out);
}

// Round 21
// 61.930 us; speedup vs baseline: 1.0221x; 1.0221x over previous
//
#include <hip/hip_runtime.h>
#include <math.h>

#define B_TOT   1024
#define L_SEQ   200
#define DIM     64
#define VOCAB   100001
#define NEG_BIG (-1e15f)
#define SEQ_ST16 66                     // bf16 row stride: 132 B -> 2-way (free) on both write & read
#define LOG2E   1.4426950408889634f
#define EB_SLACK_ROWS 512               // stage overrun slack (values masked, never used)

typedef __bf16 bf16x8 __attribute__((ext_vector_type(8)));
typedef float  f32x4  __attribute__((ext_vector_type(4)));

// raw v_exp_f32 (exp2): inputs are bounded here, denormal guard unneeded
static __device__ __forceinline__ float fast_exp2(float x) {
    return __builtin_amdgcn_exp2f(x);
}

// ---------------------------------------------------------------------------
// Kernel A: attention pooling + tail-fused convert(E->bf16).
// Phase 1: quarter-wave row cooperation — 16 lanes share one seq row,
// lane ql covers elems 4ql..4ql+3 -> every E/pos load instruction is 256 B
// CONTIGUOUS.  Dot via 4 shfl_xor.  Phases 2/3: block softmax + LDS col sum.
// Tail: grid-stride bf16 conversion of item_emb (full-grid concurrency).
// ---------------------------------------------------------------------------
__global__ __launch_bounds__(256) void pool_kernel(
    const int*   __restrict__ log_seqs,
    const float* __restrict__ item_emb,
    const float* __restrict__ attn_key,
    const float* __restrict__ pos_emb,
    float*       __restrict__ Q,
    __bf16*      __restrict__ Qb,
    __bf16*      __restrict__ Eb)
{
    const int b    = blockIdx.x;
    const int t    = threadIdx.x;
    const int wave = t >> 6;
    const int lane = t & 63;
    const int qw   = t >> 4;             // quarter-wave id 0..15
    const int ql   = t & 15;             // lane within quarter-wave

    __shared__ unsigned short s_seq16[L_SEQ][SEQ_ST16];  // 26,400 B
    __shared__ float s_sim[L_SEQ];
    __shared__ float s_attn[L_SEQ];
    __shared__ float s_red[4];
    __shared__ float s_q[4][DIM];

    // ---- phase 1: quarter-wave cooperative rows ---------------------------
    {
        const float4 key4 = ((const float4*)attn_key)[ql];   // coalesced
        const int* seq_row = log_seqs + (long)b * L_SEQ;
        #pragma unroll
        for (int it = 0; it < 13; ++it) {
            const int l = qw + it * 16;
            if (l >= L_SEQ) break;
            const int id = seq_row[l];                       // broadcast in qw
            float acc;
            if (id == 0) {
                *(ushort4*)&s_seq16[l][4 * ql] = make_ushort4(0, 0, 0, 0);
                acc = 0.f;
            } else {
                const float4 e = *(const float4*)(item_emb + (long)id * DIM + 4 * ql);
                const float4 p = *(const float4*)(pos_emb + l * DIM + 4 * ql);
                float4 f;
                f.x = fmaf(8.f, e.x, p.x);
                f.y = fmaf(8.f, e.y, p.y);
                f.z = fmaf(8.f, e.z, p.z);
                f.w = fmaf(8.f, e.w, p.w);
                ushort4 u;
                u.x = __builtin_bit_cast(unsigned short, (__bf16)f.x);
                u.y = __builtin_bit_cast(unsigned short, (__bf16)f.y);
                u.z = __builtin_bit_cast(unsigned short, (__bf16)f.z);
                u.w = __builtin_bit_cast(unsigned short, (__bf16)f.w);
                *(ushort4*)&s_seq16[l][4 * ql] = u;
                acc = f.x * key4.x + f.y * key4.y + f.z * key4.z + f.w * key4.w;
            }
            acc += __shfl_xor(acc, 1);
            acc += __shfl_xor(acc, 2);
            acc += __shfl_xor(acc, 4);
            acc += __shfl_xor(acc, 8);
            if (ql == 0) s_sim[l] = (id == 0) ? NEG_BIG : acc;
        }
    }
    __syncthreads();

    // ---- phase 2: block softmax over l -------------------------------------
    float sim = (t < L_SEQ) ? s_sim[t] : -INFINITY;
    float m = sim;
    #pragma unroll
    for (int off = 32; off > 0; off >>= 1) m = fmaxf(m, __shfl_xor(m, off));
    if (lane == 0) s_red[wave] = m;
    __syncthreads();
    m = fmaxf(fmaxf(s_red[0], s_red[1]), fmaxf(s_red[2], s_red[3]));
    __syncthreads();                             // all waves read s_red

    float p = (t < L_SEQ) ? __expf(sim - m) : 0.f;
    if (t < L_SEQ) s_attn[t] = p;
    float ls = p;
    #pragma unroll
    for (int off = 32; off > 0; off >>= 1) ls += __shfl_xor(ls, off);
    if (lane == 0) s_red[wave] = ls;
    __syncthreads();
    const float inv = 1.0f / (s_red[0] + s_red[1] + s_red[2] + s_red[3]);

    // ---- phase 3: Q accumulation from LDS, L split across waves ------------
    float q = 0.f;
    const int l0 = wave * (L_SEQ / 4);
    #pragma unroll 2
    for (int l = l0; l < l0 + (L_SEQ / 4); ++l) {
        const unsigned int ui = (unsigned int)s_seq16[l][lane] << 16;
        q = fmaf(s_attn[l], __builtin_bit_cast(float, ui), q);
    }
    s_q[wave][lane] = q;
    __syncthreads();

    if (t < DIM) {
        const float qq = (s_q[0][t] + s_q[1][t] + s_q[2][t] + s_q[3][t]) * inv;
        Q[b * DIM + t]  = qq;
        Qb[b * DIM + t] = (__bf16)(qq * LOG2E);  // exp2-domain for logits kernel
    }

    // ---- tail: convert slice of item_emb -> bf16 ---------------------------
    {
        const long n8 = ((long)VOCAB * DIM) / 8;             // 800,008 groups
        for (long g = (long)b * 256 + t; g < n8; g += (long)gridDim.x * 256) {
            const long i = g * 8;
            const float4 f0 = ((const float4*)(item_emb + i))[0];
            const float4 f1 = ((const float4*)(item_emb + i))[1];
            bf16x8 o;
            o[0] = (__bf16)f0.x; o[1] = (__bf16)f0.y; o[2] = (__bf16)f0.z; o[3] = (__bf16)f0.w;
            o[4] = (__bf16)f1.x; o[5] = (__bf16)f1.y; o[6] = (__bf16)f1.z; o[7] = (__bf16)f1.w;
            *(bf16x8*)(Eb + i) = o;
        }
    }
}

// ---------------------------------------------------------------------------
// Kernel B: bf16 MFMA logits GEMM + exp2-sum partials (R16 structure, best).
//  - block = 4 waves, 128 batch rows; wave w owns b-tiles {2w, 2w+1}
//  - per phase, 8 vtiles (16 KB) staged LDS cooperatively, XOR-swizzled
//    slot ^= (row&7)<<4; all 4 waves consume each staged vtile
//  - single buffer + 2 barriers; NC=256 -> grid 2048 = 8 blocks/CU
//  - stage overrun lands in Eb slack; tail vtile masks valid?:0
// XCD decode: chunk == xcd (mod 8); L2-resident chunk working set.
// ---------------------------------------------------------------------------
#define NC        256                   // vocab chunks
#define NBG       8                     // batch groups (1024/128)
#define VT_TOTAL  6251                  // ceil(100001/16)
#define VT_FULL   6250
#define VT_PER    25                    // ceil(VT_TOTAL/NC)
#define STAGE_VT  8                     // vtiles per stage phase (16 KB)

__global__ __launch_bounds__(256) void logits_mfma(
    const __bf16* __restrict__ Eb,      // [VOCAB+slack][64]
    const __bf16* __restrict__ Qb,      // [1024][64], exp2-domain
    float*        __restrict__ partials) // [NC][1024]
{
    const int bid   = blockIdx.x;                 // 0..2047
    const int xcd   = bid & 7;          // HW round-robins blockIdx across XCDs
    const int idx   = bid >> 3;         // 0..255 within this XCD
    const int chunk = xcd + 8 * (idx >> 3);       // chunks == xcd (mod 8)
    const int bg    = idx & 7;
    const int tid   = threadIdx.x;
    const int wave  = tid >> 6;
    const int lane  = tid & 63;
    const int r16   = lane & 15;
    const int hi    = lane >> 4;

    __shared__ char s_stage[STAGE_VT * 2048];     // 16,384 B

    bf16x8 a[2][2];
    #pragma unroll
    for (int t = 0; t < 2; ++t)
        #pragma unroll
        for (int s = 0; s < 2; ++s)
            a[t][s] = *(const bf16x8*)(Qb + ((bg*128 + (wave*2 + t)*16 + r16) * DIM) + s*32 + hi*8);

    const int vt0    = chunk * VT_PER;
    const int vt_end = min(vt0 + VT_PER, VT_TOTAL);
    const int nvt    = vt_end - vt0;
    const int nphase = nvt > 0 ? (nvt + STAGE_VT - 1) / STAGE_VT : 0;

    float ssum[2][4];
    #pragma unroll
    for (int t = 0; t < 2; ++t)
        #pragma unroll
        for (int r = 0; r < 4; ++r) ssum[t][r] = 0.f;

    // swizzled read offsets for this lane's fragment (within a 2 KB vtile)
    const int rbase = r16 * 128;
    const int x0 = (hi * 16)        ^ ((r16 & 7) << 4);
    const int x1 = ((hi * 16) + 64) ^ ((r16 & 7) << 4);

    for (int ph = 0; ph < nphase; ++ph) {
        const int vtg0 = vt0 + ph * STAGE_VT;
        __syncthreads();                          // prev compute done before overwrite
        {   // stage 8 vtiles = 128 rows x 64 cols bf16, coalesced, swizzled
            const __bf16* src = Eb + (size_t)vtg0 * 16 * DIM;
            bf16x8 v[4];
            #pragma unroll
            for (int k = 0; k < 4; ++k) {
                const int g = k * 256 + tid;      // 0..1023
                v[k] = *(const bf16x8*)(src + (size_t)(g >> 3) * DIM + (g & 7) * 8);
            }
            #pragma unroll
            for (int k = 0; k < 4; ++k) {
                const int g    = k * 256 + tid;
                const int rowg = g >> 3;          // 0..127
                const int slot = g & 7;
                const int row  = rowg & 15;
                const int vl   = rowg >> 4;
                const int db   = vl * 2048 + row * 128 + ((slot * 16) ^ ((row & 7) << 4));
                *(bf16x8*)(s_stage + db) = v[k];
            }
        }
        __syncthreads();                          // staged data visible

        const int nv = min(STAGE_VT, vt_end - vtg0);
        for (int vl = 0; vl < nv; ++vl) {
            const char* vb = s_stage + vl * 2048 + rbase;
            const bf16x8 c0 = *(const bf16x8*)(vb + x0);
            const bf16x8 c1 = *(const bf16x8*)(vb + x1);
            const int vt_g = vtg0 + vl;
            if (vt_g < VT_FULL) {
                #pragma unroll
                for (int t = 0; t < 2; ++t) {
                    f32x4 acc = {0.f, 0.f, 0.f, 0.f};
                    acc = __builtin_amdgcn_mfma_f32_16x16x32_bf16(a[t][0], c0, acc, 0, 0, 0);
                    acc = __builtin_amdgcn_mfma_f32_16x16x32_bf16(a[t][1], c1, acc, 0, 0, 0);
                    #pragma unroll
                    for (int r = 0; r < 4; ++r) ssum[t][r] += fast_exp2(acc[r]);
                }
            } else {
                const bool valid = (vt_g * 16 + r16) < VOCAB;
                #pragma unroll
                for (int t = 0; t < 2; ++t) {
                    f32x4 acc = {0.f, 0.f, 0.f, 0.f};
                    acc = __builtin_amdgcn_mfma_f32_16x16x32_bf16(a[t][0], c0, acc, 0, 0, 0);
                    acc = __builtin_amdgcn_mfma_f32_16x16x32_bf16(a[t][1], c1, acc, 0, 0, 0);
                    #pragma unroll
                    for (int r = 0; r < 4; ++r) ssum[t][r] += valid ? fast_exp2(acc[r]) : 0.f;
                }
            }
        }
    }

    // reduce exp-sums across the 16 vocab cols (lanes differing in bits 0..3)
    #pragma unroll
    for (int t = 0; t < 2; ++t)
        #pragma unroll
        for (int r = 0; r < 4; ++r) {
            float v = ssum[t][r];
            v += __shfl_xor(v, 1);
            v += __shfl_xor(v, 2);
            v += __shfl_xor(v, 4);
            v += __shfl_xor(v, 8);
            ssum[t][r] = v;
        }

    // waves own disjoint rows -> direct write, no cross-wave reduce
    if (r16 == 0) {
        #pragma unroll
        for (int t = 0; t < 2; ++t)
            #pragma unroll
            for (int r = 0; r < 4; ++r) {
                const int row = bg * 128 + (wave*2 + t) * 16 + hi * 4 + r;
                partials[(size_t)chunk * B_TOT + row] = ssum[t][r];
            }
    }
}

// ---------------------------------------------------------------------------
// Kernel C: reduce partials, exact fp32 pred logit, emit prob.
// ---------------------------------------------------------------------------
__global__ __launch_bounds__(256) void finalize_kernel(
    const float* __restrict__ Q,
    const float* __restrict__ item_emb,
    const int*   __restrict__ pred,
    const float* __restrict__ partials,
    float*       __restrict__ out)
{
    const int b = blockIdx.x * 256 + threadIdx.x;

    float S = 0.f;
    for (int c = 0; c < NC; ++c)
        S += partials[(size_t)c * B_TOT + b];

    const int pv = pred[b];
    float acc = 0.f;
    const float4* e4 = (const float4*)(item_emb + (long)pv * DIM);
    const float4* q4 = (const float4*)(Q + b * DIM);
    #pragma unroll
    for (int i = 0; i < DIM / 4; ++i) {
        const float4 e = e4[i];
        const float4 q = q4[i];
        acc += e.x*q.x + e.y*q.y + e.z*q.z + e.w*q.w;
    }
    out[b] = __expf(acc) / S;
}

// ---------------------------------------------------------------------------
extern "C" void kernel_launch(void* const* d_in, const int* in_sizes, int n_in,
                              void* d_out, int out_size, void* d_ws, size_t ws_size,
                              hipStream_t stream)
{
    const int*   log_seqs = (const int*)  d_in[0];
    const int*   pred     = (const int*)  d_in[1];
    const float* item_emb = (const float*)d_in[2];
    const float* attn_key = (const float*)d_in[3];
    const float* pos_emb  = (const float*)d_in[4];
    float*       out      = (float*)d_out;

    char* ws = (char*)d_ws;
    const size_t eb_bytes = (size_t)(VOCAB + EB_SLACK_ROWS) * DIM * 2;  // + slack
    __bf16* Eb       = (__bf16*)ws;
    __bf16* Qb       = (__bf16*)(ws + eb_bytes);                        // 131,072 B
    float*  Qf       = (float*) (ws + eb_bytes + (size_t)B_TOT * DIM * 2);
    float*  partials = (float*) ((char*)Qf + (size_t)B_TOT * DIM * 4);  // [256][1024] f32

    pool_kernel<<<B_TOT, 256, 0, stream>>>(log_seqs, item_emb, attn_key, pos_emb, Qf, Qb, Eb);
    logits_mfma<<<NBG * NC, 256, 0, stream>>>(Eb, Qb, partials);
    finalize_kernel<<<B_TOT / 256, 256, 0, stream>>>(Qf, item_emb, pred, partials, out);
}